// Round 1
// baseline (378.783 us; speedup 1.0000x reference)
//
#include <hip/hip_runtime.h>

#define EPS_DIR 1e-15f
#define EPS_W   1e-5f
#define NEAR_MIN 0.05f

// One 128-thread block per ray. T = 128 bins (127 weights), n = 128 samples.
__global__ __launch_bounds__(128) void nerf_sample_pdf_kernel(
    const float* __restrict__ rays_o,
    const float* __restrict__ rays_d,
    const float* __restrict__ weights,
    const int*   __restrict__ bound_p,
    float*       __restrict__ out,
    int R, int Tm1, int n)
{
    const int T   = Tm1 + 1;          // 128
    const int ray = blockIdx.x;
    const int tid = threadIdx.x;

    __shared__ float cdf_s[129];      // [0..T], only [0..T) used; +1 pad
    __shared__ float wsum[4];

    // ---- near/far cube intersection (redundant per-thread; broadcast loads) ----
    const float b = (float)bound_p[0];
    float nearv = -3.4e38f, farv = 3.4e38f;
#pragma unroll
    for (int k = 0; k < 3; ++k) {
        float o = rays_o[(size_t)ray * 3 + k];
        float d = rays_d[(size_t)ray * 3 + k] + EPS_DIR;
        float t0 = (-b - o) / d;
        float t1 = ( b - o) / d;
        nearv = fmaxf(nearv, fminf(t0, t1));
        farv  = fminf(farv,  fmaxf(t0, t1));
    }
    nearv = fmaxf(nearv, NEAR_MIN);

    // ---- load weight, block inclusive scan ----
    float v = (tid < Tm1) ? (weights[(size_t)ray * Tm1 + tid] + EPS_W) : 0.0f;

    float x = v;
    const int lane = tid & 63;
    const int wid  = tid >> 6;
#pragma unroll
    for (int off = 1; off < 64; off <<= 1) {
        float y = __shfl_up(x, off, 64);
        if (lane >= off) x += y;
    }
    if (lane == 63) wsum[wid] = x;
    __syncthreads();
    if (wid == 1) x += wsum[0];
    const float total = wsum[0] + wsum[1];
    const float rinv  = 1.0f / total;

    if (tid == 0) cdf_s[0] = 0.0f;
    if (tid < Tm1) cdf_s[tid + 1] = x * rinv;   // cdf_s[T-1] == 1.0f (total*rinv)
    __syncthreads();

    // ---- inverse-CDF sampling ----
    const float scale = (farv - nearv) / (float)Tm1;   // bin width factor
    const float inv_n = 1.0f / (float)n;

    for (int j = tid; j < n; j += blockDim.x) {
        float u = ((float)j + 0.5f) * inv_n;
        // searchsorted side='right': first idx in [0,T) with cdf_s[idx] > u
        int lo = 0, hi = T;
        while (lo < hi) {
            int mid = (lo + hi) >> 1;
            if (cdf_s[mid] <= u) lo = mid + 1; else hi = mid;
        }
        int below = lo - 1; if (below < 0) below = 0;
        int above = lo;     if (above > T - 1) above = T - 1;

        float c_lo = cdf_s[below];
        float c_hi = cdf_s[above];
        float denom = c_hi - c_lo;
        denom = (denom < EPS_W) ? 1.0f : denom;
        float t = (u - c_lo) / denom;

        float bin_lo = nearv + scale * (float)below;
        float bin_hi = nearv + scale * (float)above;
        out[(size_t)ray * n + j] = bin_lo + t * (bin_hi - bin_lo);
    }
}

extern "C" void kernel_launch(void* const* d_in, const int* in_sizes, int n_in,
                              void* d_out, int out_size, void* d_ws, size_t ws_size,
                              hipStream_t stream) {
    const float* rays_o  = (const float*)d_in[0];
    const float* rays_d  = (const float*)d_in[1];
    const float* weights = (const float*)d_in[2];
    const int*   bound_p = (const int*)d_in[3];
    float*       out     = (float*)d_out;

    const int R   = in_sizes[0] / 3;       // 262144 rays
    const int Tm1 = in_sizes[2] / R;       // 127 weights per ray
    const int n   = out_size / R;          // 128 samples per ray

    dim3 grid(R), block(Tm1 + 1);          // 128 threads = 2 waves
    nerf_sample_pdf_kernel<<<grid, block, 0, stream>>>(
        rays_o, rays_d, weights, bound_p, out, R, Tm1, n);
}

// Round 2
// 336.596 us; speedup vs baseline: 1.1253x; 1.1253x over previous
//
#include <hip/hip_runtime.h>

#define EPS_DIR 1e-15f
#define EPS_W   1e-5f
#define NEAR_MIN 0.05f

// One 128-thread block (2 waves) per ray. T = 128 bins (127 weights), n = 128 samples.
// Inverse-CDF sampling WITHOUT binary search: thread i owns cdf interval
// [cdf[i], cdf[i+1]) and scatters the samples falling inside it. Since u_j =
// (j+0.5)/n is a uniform grid, the sample range is a closed-form ceil().
// Adjacent threads derive the shared boundary from bit-identical floats, so
// the ranges exactly partition [0, n) -> every output written exactly once.
__global__ __launch_bounds__(128) void nerf_sample_pdf_kernel(
    const float* __restrict__ rays_o,
    const float* __restrict__ rays_d,
    const float* __restrict__ weights,
    const int*   __restrict__ bound_p,
    float*       __restrict__ out,
    int R, int Tm1, int n)
{
    const int ray  = blockIdx.x;
    const int tid  = threadIdx.x;
    const int lane = tid & 63;
    const int wid  = tid >> 6;

    __shared__ float wsum[2];

    // ---- load weight (coalesced), wave-level inclusive scan ----
    float v = (tid < Tm1) ? (weights[(size_t)ray * Tm1 + tid] + EPS_W) : 0.0f;
    float x = v;
#pragma unroll
    for (int off = 1; off < 64; off <<= 1) {
        float y = __shfl_up(x, off, 64);
        if (lane >= off) x += y;
    }
    if (lane == 63) wsum[wid] = x;

    // ---- near/far cube intersection (fast rcp; redundant per-thread) ----
    const float b = (float)bound_p[0];
    float nearv = -3.4e38f, farv = 3.4e38f;
#pragma unroll
    for (int k = 0; k < 3; ++k) {
        float o = rays_o[(size_t)ray * 3 + k];
        float d = rays_d[(size_t)ray * 3 + k] + EPS_DIR;
        float r = __builtin_amdgcn_rcpf(d);
        float t0 = (-b - o) * r;
        float t1 = ( b - o) * r;
        nearv = fmaxf(nearv, fminf(t0, t1));
        farv  = fminf(farv,  fmaxf(t0, t1));
    }
    nearv = fmaxf(nearv, NEAR_MIN);

    __syncthreads();
    const float w0    = wsum[0];
    const float total = w0 + wsum[1];
    const float rinv  = __builtin_amdgcn_rcpf(total);

    // block-level inclusive scan; cdf[tid+1] = xx * rinv
    const float xx    = x + (wid ? w0 : 0.0f);
    const float c_hi  = xx * rinv;
    const float xprev = __shfl_up(xx, 1, 64);
    float c_lo;
    if (lane == 0) c_lo = (wid == 0) ? 0.0f : w0 * rinv;  // == thread 63's c_hi bits
    else           c_lo = xprev * rinv;                   // == prev thread's c_hi bits

    if (tid < Tm1) {
        const float denom  = c_hi - c_lo;
        const float rdenom = (denom < EPS_W) ? 1.0f : __builtin_amdgcn_rcpf(denom);
        const float scale  = (farv - nearv) * __builtin_amdgcn_rcpf((float)Tm1);
        const float inv_n  = 1.0f / (float)n;
        const float fn     = (float)n;

        // sample range for this interval: u_j in [c_lo, c_hi)  <=>  j in [j0, j1)
        int j0 = (int)ceilf(fn * c_lo - 0.5f);
        if (j0 < 0) j0 = 0;
        int j1;
        if (tid == Tm1 - 1) {
            j1 = n;                               // last interval absorbs the tail
        } else {
            j1 = (int)ceilf(fn * c_hi - 0.5f);
            if (j1 > n) j1 = n;
        }

        const float zbase = nearv + scale * (float)tid;   // bin_lo
        float* __restrict__ orow = out + (size_t)ray * n;
        for (int j = j0; j < j1; ++j) {
            float u = ((float)j + 0.5f) * inv_n;
            float t = (u - c_lo) * rdenom;
            orow[j] = fmaf(t, scale, zbase);
        }
    }
}

extern "C" void kernel_launch(void* const* d_in, const int* in_sizes, int n_in,
                              void* d_out, int out_size, void* d_ws, size_t ws_size,
                              hipStream_t stream) {
    const float* rays_o  = (const float*)d_in[0];
    const float* rays_d  = (const float*)d_in[1];
    const float* weights = (const float*)d_in[2];
    const int*   bound_p = (const int*)d_in[3];
    float*       out     = (float*)d_out;

    const int R   = in_sizes[0] / 3;       // 262144 rays
    const int Tm1 = in_sizes[2] / R;       // 127 weights per ray
    const int n   = out_size / R;          // 128 samples per ray

    dim3 grid(R), block(Tm1 + 1);          // 128 threads = 2 waves
    nerf_sample_pdf_kernel<<<grid, block, 0, stream>>>(
        rays_o, rays_d, weights, bound_p, out, R, Tm1, n);
}

// Round 3
// 284.122 us; speedup vs baseline: 1.3332x; 1.1847x over previous
//
#include <hip/hip_runtime.h>

#define EPS_DIR 1e-15f
#define EPS_W   1e-5f
#define NEAR_MIN 0.05f

// One WAVE (64 lanes) per ray; 4 rays per 256-thread block. Each lane owns
// two adjacent weights -> two CDF intervals. No LDS, no __syncthreads.
// Inverse-CDF sampling by interval-ownership scatter: lane t owns
// cdf range [c_lo, c_hi) (its two intervals), and writes samples
// j in [ceil(n*c_lo-0.5), ceil(n*c_hi-0.5)). Adjacent lanes derive the
// shared boundary from bit-identical floats (shfl of the inclusive scan),
// so ranges exactly partition [0, n).
__global__ __launch_bounds__(256) void nerf_sample_pdf_kernel(
    const float* __restrict__ rays_o,
    const float* __restrict__ rays_d,
    const float* __restrict__ weights,
    const int*   __restrict__ bound_p,
    float*       __restrict__ out,
    int R, int Tm1, int n)
{
    const int lane = threadIdx.x & 63;
    const int wid  = threadIdx.x >> 6;
    const int ray  = blockIdx.x * 4 + wid;
    if (ray >= R) return;

    // ---- load 2 weights per lane (two stride-2 coalesced loads) ----
    const float* wrow = weights + (size_t)ray * Tm1;
    const int i0 = 2 * lane, i1 = 2 * lane + 1;
    float w0 = (i0 < Tm1) ? (wrow[i0] + EPS_W) : 0.0f;
    float w1 = (i1 < Tm1) ? (wrow[i1] + EPS_W) : 0.0f;
    const float local = w0 + w1;

    // ---- wave inclusive scan of pair-sums ----
    float S = local;
#pragma unroll
    for (int off = 1; off < 64; off <<= 1) {
        float y = __shfl_up(S, off, 64);
        if (lane >= off) S += y;
    }
    const float total = __shfl(S, 63, 64);
    const float rinv  = __builtin_amdgcn_rcpf(total);

    // exclusive prefix: exact bits of previous lane's inclusive sum
    float prevS = __shfl_up(S, 1, 64);
    if (lane == 0) prevS = 0.0f;

    const float c_lo  = prevS * rinv;            // == lane-1's c_hi bits
    const float c_hi  = S * rinv;
    const float c_mid = (prevS + w0) * rinv;     // internal boundary (local only)

    // ---- near/far cube intersection (wave-uniform; fast rcp) ----
    const float b = (float)bound_p[0];
    float nearv = -3.4e38f, farv = 3.4e38f;
#pragma unroll
    for (int k = 0; k < 3; ++k) {
        float o = rays_o[(size_t)ray * 3 + k];
        float d = rays_d[(size_t)ray * 3 + k] + EPS_DIR;
        float r = __builtin_amdgcn_rcpf(d);
        float t0 = (-b - o) * r;
        float t1 = ( b - o) * r;
        nearv = fmaxf(nearv, fminf(t0, t1));
        farv  = fminf(farv,  fmaxf(t0, t1));
    }
    nearv = fmaxf(nearv, NEAR_MIN);

    // ---- per-interval interp coefficients ----
    const float scale = (farv - nearv) * __builtin_amdgcn_rcpf((float)Tm1);
    const float d0 = c_mid - c_lo;
    const float d1 = c_hi - c_mid;
    const float rden0 = (d0 < EPS_W) ? 1.0f : __builtin_amdgcn_rcpf(d0);
    const float rden1 = (d1 < EPS_W) ? 1.0f : __builtin_amdgcn_rcpf(d1);
    const float zb0 = nearv + scale * (float)i0;   // bin_lo of interval i0
    const float zb1 = zb0 + scale;                 // bin_lo of interval i1

    const float fn    = (float)n;
    const float inv_n = 1.0f / fn;

    // sample index range owned by this lane (exact partition of [0,n))
    int j0 = (int)ceilf(fn * c_lo - 0.5f);
    if (j0 < 0) j0 = 0;
    int j1;
    const bool last = (i1 >= Tm1 - 1);             // lane holding the final interval
    if (last) {
        j1 = n;                                    // absorb tail (u ~ 1 vs rcp rounding)
    } else {
        j1 = (int)ceilf(fn * c_hi - 0.5f);
        if (j1 > n) j1 = n;
    }

    float* __restrict__ orow = out + (size_t)ray * n;
    for (int j = j0; j < j1; ++j) {
        float u = ((float)j + 0.5f) * inv_n;
        bool second = (u >= c_mid) && (i1 < Tm1);  // pick interval i1 vs i0
        float lo  = second ? c_mid : c_lo;
        float rd  = second ? rden1 : rden0;
        float zb  = second ? zb1   : zb0;
        float t   = (u - lo) * rd;
        orow[j] = fmaf(t, scale, zb);
    }
}

extern "C" void kernel_launch(void* const* d_in, const int* in_sizes, int n_in,
                              void* d_out, int out_size, void* d_ws, size_t ws_size,
                              hipStream_t stream) {
    const float* rays_o  = (const float*)d_in[0];
    const float* rays_d  = (const float*)d_in[1];
    const float* weights = (const float*)d_in[2];
    const int*   bound_p = (const int*)d_in[3];
    float*       out     = (float*)d_out;

    const int R   = in_sizes[0] / 3;       // 262144 rays
    const int Tm1 = in_sizes[2] / R;       // 127 weights per ray
    const int n   = out_size / R;          // 128 samples per ray

    dim3 grid((R + 3) / 4), block(256);    // 4 waves/block = 4 rays/block
    nerf_sample_pdf_kernel<<<grid, block, 0, stream>>>(
        rays_o, rays_d, weights, bound_p, out, R, Tm1, n);
}